// Round 5
// baseline (418.183 us; speedup 1.0000x reference)
//
#include <hip/hip_runtime.h>

// ---------- types ----------
typedef float f32x4 __attribute__((ext_vector_type(4)));
typedef __bf16 bf16x8 __attribute__((ext_vector_type(8)));
typedef short s16x8 __attribute__((ext_vector_type(8)));
typedef int i32x4 __attribute__((ext_vector_type(4)));

// f32 -> bf16 round-to-nearest-even
__device__ __forceinline__ unsigned short f2bf(float f) {
  union { float f; unsigned u; } v;
  v.f = f;
  unsigned r = v.u + 0x7FFFu + ((v.u >> 16) & 1u);
  return (unsigned short)(r >> 16);
}

// pack two f32 -> packed bf16x2 (round-half-up via +0x8000, then byte-perm)
__device__ __forceinline__ int pk2bf(float lo, float hi) {
  unsigned a = __builtin_bit_cast(unsigned, lo) + 0x8000u;
  unsigned b = __builtin_bit_cast(unsigned, hi) + 0x8000u;
  return (int)__builtin_amdgcn_perm(b, a, 0x07060302u);
}

#if __has_builtin(__builtin_amdgcn_exp2f)
__device__ __forceinline__ float fexp2(float x) { return __builtin_amdgcn_exp2f(x); }
#else
__device__ __forceinline__ float fexp2(float x) { return exp2f(x); }
#endif

// async 16B global->LDS (wave-uniform base + lane*16; our mappings respect this)
__device__ __forceinline__ void gl_lds16(const void* g, void* l) {
  __builtin_amdgcn_global_load_lds(
      (__attribute__((address_space(1))) void*)g,
      (__attribute__((address_space(3))) void*)l, 16, 0, 0);
}

// ---------- pre-pass kernels ----------
__global__ __launch_bounds__(256) void k_convert_x(const float* __restrict__ in,
                                                   short* __restrict__ out) {
  int i = (blockIdx.x * 256 + threadIdx.x) * 8;
  const float4* p = (const float4*)(in + i);
  float4 a = p[0], b = p[1];
  s16x8 r;
  r[0] = (short)f2bf(a.x); r[1] = (short)f2bf(a.y);
  r[2] = (short)f2bf(a.z); r[3] = (short)f2bf(a.w);
  r[4] = (short)f2bf(b.x); r[5] = (short)f2bf(b.y);
  r[6] = (short)f2bf(b.z); r[7] = (short)f2bf(b.w);
  *(s16x8*)(out + i) = r;
}

// in: [R,C] f32 row-major -> out: [C,R] bf16 row-major
__global__ __launch_bounds__(256) void k_transpose_cvt(const float* __restrict__ in,
                                                       short* __restrict__ out,
                                                       int R, int C) {
  __shared__ short tile[32][33];
  int c0 = blockIdx.x * 32, r0 = blockIdx.y * 32;
  int tx = threadIdx.x, ty = threadIdx.y;
#pragma unroll
  for (int i = 0; i < 32; i += 8)
    tile[ty + i][tx] = (short)f2bf(in[(size_t)(r0 + ty + i) * C + c0 + tx]);
  __syncthreads();
#pragma unroll
  for (int i = 0; i < 32; i += 8)
    out[(size_t)(c0 + ty + i) * R + r0 + tx] = tile[tx][ty + i];
}

// ---------- QKV GEMM (BK=32, round-3 verbatim): C[8192,3072] = Xbf @ WinT^T + b ----------
__global__ __launch_bounds__(256) void k_qkv_gemm(const short* __restrict__ A,
                                                  const short* __restrict__ B,
                                                  const float* __restrict__ bias,
                                                  short* __restrict__ qb,
                                                  short* __restrict__ kb,
                                                  short* __restrict__ vtb) {
  __shared__ short As[128 * 32];
  __shared__ short Bs[128 * 32];
  const int tid = threadIdx.x;
  const int lane = tid & 63;
  const int w = tid >> 6;
  const int g = lane >> 4, c = lane & 15;
  const int m0 = blockIdx.y * 128, n0 = blockIdx.x * 128;
  const int wm = (w >> 1) * 64, wn = (w & 1) * 64;
  f32x4 acc[4][4] = {};
  const int p0 = tid, p1 = tid + 256;
  const int rowA0 = p0 >> 2, logA0 = (p0 & 3) ^ ((p0 >> 3) & 3);
  const int rowA1 = p1 >> 2, logA1 = (p1 & 3) ^ ((p1 >> 3) & 3);
  const short* a0 = A + (size_t)(m0 + rowA0) * 1024 + logA0 * 8;
  const short* a1 = A + (size_t)(m0 + rowA1) * 1024 + logA1 * 8;
  const short* b0 = B + (size_t)(n0 + rowA0) * 1024 + logA0 * 8;
  const short* b1 = B + (size_t)(n0 + rowA1) * 1024 + logA1 * 8;
  short* lA0 = As + p0 * 8; short* lA1 = As + p1 * 8;
  short* lB0 = Bs + p0 * 8; short* lB1 = Bs + p1 * 8;

  for (int k0 = 0; k0 < 1024; k0 += 32) {
    gl_lds16(a0 + k0, lA0);
    gl_lds16(a1 + k0, lA1);
    gl_lds16(b0 + k0, lB0);
    gl_lds16(b1 + k0, lB1);
    __syncthreads();
    bf16x8 af[4], bfr[4];
#pragma unroll
    for (int t = 0; t < 4; t++) {
      int ra = wm + t * 16 + c;
      af[t] = *(const bf16x8*)(As + ra * 32 + (g ^ ((ra >> 1) & 3)) * 8);
      int rb = wn + t * 16 + c;
      bfr[t] = *(const bf16x8*)(Bs + rb * 32 + (g ^ ((rb >> 1) & 3)) * 8);
    }
#pragma unroll
    for (int i = 0; i < 4; i++)
#pragma unroll
      for (int jn = 0; jn < 4; jn++)
        acc[i][jn] = __builtin_amdgcn_mfma_f32_16x16x32_bf16(af[i], bfr[jn], acc[i][jn], 0, 0, 0);
    __syncthreads();
  }

  const int which = n0 >> 10;  // block-uniform: 0=Q 1=K 2=V
  const float qscale = 0.125f * 1.4426950408889634f;
  if (which == 2) {
#pragma unroll
    for (int jn = 0; jn < 4; jn++) {
      const int col = n0 + wn + jn * 16 + c;
      const float bv = bias[col];
      const int cw = col & 1023;
      const int h = cw >> 6, d = cw & 63;
#pragma unroll
      for (int i = 0; i < 4; i++) {
        const int row = m0 + wm + i * 16 + g * 4;
        const int bb = row >> 11, l0 = row & 2047;
        int lo = pk2bf(acc[i][jn][0] + bv, acc[i][jn][1] + bv);
        int hi = pk2bf(acc[i][jn][2] + bv, acc[i][jn][3] + bv);
        *(int2*)(vtb + (size_t)((bb * 16 + h) * 64 + d) * 2048 + l0) = make_int2(lo, hi);
      }
    }
  } else {
    short* dst = (which == 0) ? qb : kb;
    const float sc = (which == 0) ? qscale : 1.0f;
#pragma unroll
    for (int jn = 0; jn < 4; jn++) {
      const int col = n0 + wn + jn * 16 + c;
      const float bv = bias[col];
      const int cw = col & 1023;
      const int h = cw >> 6, d = cw & 63;
#pragma unroll
      for (int i = 0; i < 4; i++) {
#pragma unroll
        for (int r = 0; r < 4; r++) {
          const int row = m0 + wm + i * 16 + g * 4 + r;
          const int bb = row >> 11, l = row & 2047;
          dst[((size_t)((bb * 16 + h) * 2048 + l) << 6) + d] = (short)f2bf((acc[i][jn][r] + bv) * sc);
        }
      }
    }
  }
}

// stage one 128-key K tile + V^T tile into LDS (async, all 512 threads)
__device__ __forceinline__ void stage_kv512(const short* __restrict__ Kt,
                                            const short* __restrict__ Vtt,
                                            short* ksb, short* vsb, int tid) {
#pragma unroll
  for (int t = 0; t < 2; t++) {
    int p = tid + t * 512;
    int krow = p >> 3, kchk = (p & 7) ^ (krow & 7);
    gl_lds16(Kt + (size_t)krow * 64 + kchk * 8, ksb + p * 8);
    int dv = p >> 4, vchk = (p & 15) ^ (dv & 15);
    gl_lds16(Vtt + (size_t)dv * 2048 + vchk * 8, vsb + p * 8);
  }
}

// ---------- flash attention (S^T form, dual-tile 512-thread blocks) ----------
// One block = (bh, pr): waves 0-3 compute query tile qt=15-pr, waves 4-7 qt=pr,
// SHARING one double-buffered K/V stream of (16-pr) tiles. Total compute per
// block = 17 wave-tiles (balanced); KV streaming 100 tile-loads vs 136 before.
// 2 blocks/CU x 8 waves = 4 waves/SIMD (2x round-3 hiding).
__global__ __launch_bounds__(512, 4) void k_attn(const short* __restrict__ Q,
                                                 const short* __restrict__ K,
                                                 const short* __restrict__ Vt,
                                                 short* __restrict__ O) {
  __shared__ short Ks[2][128 * 64];  // 2x16 KB [key][d], 8-chunk XOR swizzle
  __shared__ short Vs[2][64 * 128];  // 2x16 KB [d][key], 16-chunk XOR swizzle
  const int tid = threadIdx.x;       // 0..511
  const int lane = tid & 63;
  const int w = tid >> 6;            // 0..7
  const int wq = w & 3;              // 32-query sub-tile within the wave's query tile
  const int quad = lane >> 4, cq = lane & 15;
  const int bh = blockIdx.y;
  const int bb = bh >> 4, h = bh & 15;
  const size_t base = (size_t)bh * (2048 * 64);
  const int pr = blockIdx.x;         // 0..7
  const int myqt = (w < 4) ? (15 - pr) : pr;  // wave's query tile
  const int jmax = 15 - pr;          // last KV tile streamed by this block
  const int m0 = myqt * 128;
  const int sA = cq | (((2 * quad) & 3) << 4);
  const int sB = cq | (((2 * quad + 1) & 3) << 4);

  // Q B-frags straight from global (16B/lane)
  bf16x8 qf[2][2];
#pragma unroll
  for (int mt = 0; mt < 2; mt++)
#pragma unroll
    for (int kd = 0; kd < 2; kd++)
      qf[mt][kd] = *(const bf16x8*)(Q + base +
          (size_t)(m0 + wq * 32 + mt * 16 + cq) * 64 + (kd * 4 + quad) * 8);

  stage_kv512(K + base, Vt + base, Ks[0], Vs[0], tid);

  f32x4 o[2][4] = {};
  float m_run[2] = {-1e30f, -1e30f};
  float l_run[2] = {0.f, 0.f};

  for (int j = 0; j <= jmax; j++) {
    const int cur = j & 1;
    __syncthreads();  // buf[cur] staged; buf[cur^1] fully consumed
    if (j < jmax)
      stage_kv512(K + base + (size_t)(j + 1) * 128 * 64, Vt + base + (j + 1) * 128,
                  Ks[cur ^ 1], Vs[cur ^ 1], tid);
    if (j <= myqt) {  // wave-uniform guard
      const short* ks = Ks[cur];
      const short* vs = Vs[cur];

      // S^T[key][q] : per wave 128 keys x 32 queries
      f32x4 s[2][8] = {};
#pragma unroll
      for (int kd = 0; kd < 2; kd++)
#pragma unroll
        for (int nt = 0; nt < 8; nt++) {
          int krow = nt * 16 + cq;
          bf16x8 kf = *(const bf16x8*)(ks + krow * 64 + ((kd * 4 + quad) ^ (krow & 7)) * 8);
          s[0][nt] = __builtin_amdgcn_mfma_f32_16x16x32_bf16(kf, qf[0][kd], s[0][nt], 0, 0, 0);
          s[1][nt] = __builtin_amdgcn_mfma_f32_16x16x32_bf16(kf, qf[1][kd], s[1][nt], 0, 0, 0);
        }

      const bool diag = (j == myqt);
      bf16x8 pf[2][4];
#pragma unroll
      for (int mt = 0; mt < 2; mt++) {
        float mx = -1e30f;
        if (diag) {
          int qloc = wq * 32 + mt * 16 + cq;
#pragma unroll
          for (int nt = 0; nt < 8; nt++)
#pragma unroll
            for (int r = 0; r < 4; r++) {
              float v = (nt * 16 + quad * 4 + r > qloc) ? -1e30f : s[mt][nt][r];
              s[mt][nt][r] = v;
              mx = fmaxf(mx, v);
            }
        } else {
#pragma unroll
          for (int nt = 0; nt < 8; nt++)
#pragma unroll
            for (int r = 0; r < 4; r++) mx = fmaxf(mx, s[mt][nt][r]);
        }
        mx = fmaxf(mx, __shfl_xor(mx, 16));
        mx = fmaxf(mx, __shfl_xor(mx, 32));
        const float mn = fmaxf(m_run[mt], mx);
        const float alpha = fexp2(m_run[mt] - mn);
        m_run[mt] = mn;
        float lt = 0.f;
#pragma unroll
        for (int nt = 0; nt < 8; nt++)
#pragma unroll
          for (int r = 0; r < 4; r++) {
            float p = fexp2(s[mt][nt][r] - mn);
            s[mt][nt][r] = p;
            lt += p;
          }
        l_run[mt] = l_run[mt] * alpha + lt;
#pragma unroll
        for (int dn = 0; dn < 4; dn++) o[mt][dn] *= alpha;
        // P^T (C-layout) -> PV B-frag: pack pairs, route across quads
#pragma unroll
        for (int kt = 0; kt < 4; kt++) {
          int dA0 = pk2bf(s[mt][2 * kt][0], s[mt][2 * kt][1]);
          int dA1 = pk2bf(s[mt][2 * kt][2], s[mt][2 * kt][3]);
          int dB0 = pk2bf(s[mt][2 * kt + 1][0], s[mt][2 * kt + 1][1]);
          int dB1 = pk2bf(s[mt][2 * kt + 1][2], s[mt][2 * kt + 1][3]);
          i32x4 ow;
          {
            int t0 = __shfl(dA0, sA, 64), t1 = __shfl(dB0, sA, 64);
            ow[0] = (quad < 2) ? t0 : t1;
          }
          {
            int t0 = __shfl(dA1, sA, 64), t1 = __shfl(dB1, sA, 64);
            ow[1] = (quad < 2) ? t0 : t1;
          }
          {
            int t0 = __shfl(dA0, sB, 64), t1 = __shfl(dB0, sB, 64);
            ow[2] = (quad < 2) ? t0 : t1;
          }
          {
            int t0 = __shfl(dA1, sB, 64), t1 = __shfl(dB1, sB, 64);
            ow[3] = (quad < 2) ? t0 : t1;
          }
          pf[mt][kt] = __builtin_bit_cast(bf16x8, ow);
        }
      }

      // O^T += Vt * P  (A=Vt frag, B=P frag)
#pragma unroll
      for (int kt = 0; kt < 4; kt++)
#pragma unroll
        for (int dn = 0; dn < 4; dn++) {
          int drow = dn * 16 + cq;
          bf16x8 vtf = *(const bf16x8*)(vs + drow * 128 + ((kt * 4 + quad) ^ (drow & 15)) * 8);
          o[0][dn] = __builtin_amdgcn_mfma_f32_16x16x32_bf16(vtf, pf[0][kt], o[0][dn], 0, 0, 0);
          o[1][dn] = __builtin_amdgcn_mfma_f32_16x16x32_bf16(vtf, pf[1][kt], o[1][dn], 0, 0, 0);
        }
    }
  }

  // epilogue: reduce l across quads, normalize, pack 4 consecutive d -> 8B store
#pragma unroll
  for (int mt = 0; mt < 2; mt++) {
    float lf = l_run[mt];
    lf += __shfl_xor(lf, 16);
    lf += __shfl_xor(lf, 32);
    const float inv = 1.f / lf;
    const size_t rb = ((size_t)(bb * 2048 + m0 + wq * 32 + mt * 16 + cq)) * 1024 + h * 64;
#pragma unroll
    for (int dn = 0; dn < 4; dn++) {
      int d0 = pk2bf(o[mt][dn][0] * inv, o[mt][dn][1] * inv);
      int d1 = pk2bf(o[mt][dn][2] * inv, o[mt][dn][3] * inv);
      *(int2*)(O + rb + dn * 16 + quad * 4) = make_int2(d0, d1);
    }
  }
}

// ---------- out GEMM (BK=32, round-3 verbatim): out[8192,1024] = AO @ WoutT^T + b ----------
__global__ __launch_bounds__(256) void k_out_gemm(const short* __restrict__ A,
                                                  const short* __restrict__ B,
                                                  const float* __restrict__ bias,
                                                  float* __restrict__ out) {
  __shared__ short As[128 * 32];
  __shared__ short Bs[128 * 32];
  const int tid = threadIdx.x;
  const int lane = tid & 63;
  const int w = tid >> 6;
  const int g = lane >> 4, c = lane & 15;
  const int m0 = blockIdx.y * 128, n0 = blockIdx.x * 128;
  const int wm = (w >> 1) * 64, wn = (w & 1) * 64;
  f32x4 acc[4][4] = {};
  const int p0 = tid, p1 = tid + 256;
  const int rowA0 = p0 >> 2, logA0 = (p0 & 3) ^ ((p0 >> 3) & 3);
  const int rowA1 = p1 >> 2, logA1 = (p1 & 3) ^ ((p1 >> 3) & 3);
  const short* a0 = A + (size_t)(m0 + rowA0) * 1024 + logA0 * 8;
  const short* a1 = A + (size_t)(m0 + rowA1) * 1024 + logA1 * 8;
  const short* b0 = B + (size_t)(n0 + rowA0) * 1024 + logA0 * 8;
  const short* b1 = B + (size_t)(n0 + rowA1) * 1024 + logA1 * 8;
  short* lA0 = As + p0 * 8; short* lA1 = As + p1 * 8;
  short* lB0 = Bs + p0 * 8; short* lB1 = Bs + p1 * 8;

  for (int k0 = 0; k0 < 1024; k0 += 32) {
    gl_lds16(a0 + k0, lA0);
    gl_lds16(a1 + k0, lA1);
    gl_lds16(b0 + k0, lB0);
    gl_lds16(b1 + k0, lB1);
    __syncthreads();
    bf16x8 af[4], bfr[4];
#pragma unroll
    for (int t = 0; t < 4; t++) {
      int ra = wm + t * 16 + c;
      af[t] = *(const bf16x8*)(As + ra * 32 + (g ^ ((ra >> 1) & 3)) * 8);
      int rb = wn + t * 16 + c;
      bfr[t] = *(const bf16x8*)(Bs + rb * 32 + (g ^ ((rb >> 1) & 3)) * 8);
    }
#pragma unroll
    for (int i = 0; i < 4; i++)
#pragma unroll
      for (int jn = 0; jn < 4; jn++)
        acc[i][jn] = __builtin_amdgcn_mfma_f32_16x16x32_bf16(af[i], bfr[jn], acc[i][jn], 0, 0, 0);
    __syncthreads();
  }
#pragma unroll
  for (int jn = 0; jn < 4; jn++) {
    const int col = n0 + wn + jn * 16 + c;
    const float bv = bias[col];
#pragma unroll
    for (int i = 0; i < 4; i++) {
#pragma unroll
      for (int r = 0; r < 4; r++) {
        const int row = m0 + wm + i * 16 + g * 4 + r;
        out[(size_t)row * 1024 + col] = acc[i][jn][r] + bv;
      }
    }
  }
}

// ---------- launch ----------
extern "C" void kernel_launch(void* const* d_in, const int* in_sizes, int n_in,
                              void* d_out, int out_size, void* d_ws, size_t ws_size,
                              hipStream_t stream) {
  const float* x     = (const float*)d_in[0];
  const float* w_in  = (const float*)d_in[1];
  const float* b_in  = (const float*)d_in[2];
  const float* w_out = (const float*)d_in[3];
  const float* b_out = (const float*)d_in[4];
  float* out = (float*)d_out;
  char* ws = (char*)d_ws;
  short* x_bf   = (short*)(ws);                      // 16 MB  [8192,1024] bf16
  short* w_inT  = (short*)(ws + (16ull << 20));      //  6 MB  [3072,1024] bf16
  short* w_outT = (short*)(ws + (22ull << 20));      //  2 MB  [1024,1024] bf16
  short* qb     = (short*)(ws + (24ull << 20));      // 16 MB  [B,H,L,64]  bf16 (pre-scaled)
  short* kb     = (short*)(ws + (40ull << 20));      // 16 MB  [B,H,L,64]  bf16
  short* vtb    = (short*)(ws + (56ull << 20));      // 16 MB  [B,H,64,L]  bf16
  short* ao     = (short*)(ws + (72ull << 20));      // 16 MB  [B,L,H*64]  bf16

  k_convert_x<<<dim3(4096), dim3(256), 0, stream>>>(x, x_bf);
  k_transpose_cvt<<<dim3(96, 32), dim3(32, 8), 0, stream>>>(w_in, w_inT, 1024, 3072);
  k_transpose_cvt<<<dim3(32, 32), dim3(32, 8), 0, stream>>>(w_out, w_outT, 1024, 1024);
  k_qkv_gemm<<<dim3(24, 64), dim3(256), 0, stream>>>(x_bf, w_inT, b_in, qb, kb, vtb);
  k_attn<<<dim3(8, 64), dim3(512), 0, stream>>>(qb, kb, vtb, ao);
  k_out_gemm<<<dim3(8, 64), dim3(256), 0, stream>>>(ao, w_outT, b_out, out);
}

// Round 6
// 295.000 us; speedup vs baseline: 1.4176x; 1.4176x over previous
//
#include <hip/hip_runtime.h>

// ---------- types ----------
typedef float f32x4 __attribute__((ext_vector_type(4)));
typedef __bf16 bf16x8 __attribute__((ext_vector_type(8)));
typedef short s16x8 __attribute__((ext_vector_type(8)));
typedef int i32x4 __attribute__((ext_vector_type(4)));

// f32 -> bf16 round-to-nearest-even
__device__ __forceinline__ unsigned short f2bf(float f) {
  union { float f; unsigned u; } v;
  v.f = f;
  unsigned r = v.u + 0x7FFFu + ((v.u >> 16) & 1u);
  return (unsigned short)(r >> 16);
}

// pack two f32 -> packed bf16x2 (round-half-up via +0x8000, then byte-perm)
__device__ __forceinline__ int pk2bf(float lo, float hi) {
  unsigned a = __builtin_bit_cast(unsigned, lo) + 0x8000u;
  unsigned b = __builtin_bit_cast(unsigned, hi) + 0x8000u;
  return (int)__builtin_amdgcn_perm(b, a, 0x07060302u);
}

#if __has_builtin(__builtin_amdgcn_exp2f)
__device__ __forceinline__ float fexp2(float x) { return __builtin_amdgcn_exp2f(x); }
#else
__device__ __forceinline__ float fexp2(float x) { return exp2f(x); }
#endif

// async 16B global->LDS (wave-uniform base + lane*16; our mappings respect this)
__device__ __forceinline__ void gl_lds16(const void* g, void* l) {
  __builtin_amdgcn_global_load_lds(
      (__attribute__((address_space(1))) void*)g,
      (__attribute__((address_space(3))) void*)l, 16, 0, 0);
}

// ---------- pre-pass kernels ----------
__global__ __launch_bounds__(256) void k_convert_x(const float* __restrict__ in,
                                                   short* __restrict__ out) {
  int i = (blockIdx.x * 256 + threadIdx.x) * 8;
  const float4* p = (const float4*)(in + i);
  float4 a = p[0], b = p[1];
  s16x8 r;
  r[0] = (short)f2bf(a.x); r[1] = (short)f2bf(a.y);
  r[2] = (short)f2bf(a.z); r[3] = (short)f2bf(a.w);
  r[4] = (short)f2bf(b.x); r[5] = (short)f2bf(b.y);
  r[6] = (short)f2bf(b.z); r[7] = (short)f2bf(b.w);
  *(s16x8*)(out + i) = r;
}

// in: [R,C] f32 row-major -> out: [C,R] bf16 row-major
__global__ __launch_bounds__(256) void k_transpose_cvt(const float* __restrict__ in,
                                                       short* __restrict__ out,
                                                       int R, int C) {
  __shared__ short tile[32][33];
  int c0 = blockIdx.x * 32, r0 = blockIdx.y * 32;
  int tx = threadIdx.x, ty = threadIdx.y;
#pragma unroll
  for (int i = 0; i < 32; i += 8)
    tile[ty + i][tx] = (short)f2bf(in[(size_t)(r0 + ty + i) * C + c0 + tx]);
  __syncthreads();
#pragma unroll
  for (int i = 0; i < 32; i += 8)
    out[(size_t)(c0 + ty + i) * R + r0 + tx] = tile[tx][ty + i];
}

// ---------- QKV GEMM (BK=32): C[8192,3072] = Xbf @ WinT^T + b ----------
__global__ __launch_bounds__(256) void k_qkv_gemm(const short* __restrict__ A,
                                                  const short* __restrict__ B,
                                                  const float* __restrict__ bias,
                                                  short* __restrict__ qb,
                                                  short* __restrict__ kb,
                                                  short* __restrict__ vtb) {
  __shared__ short As[128 * 32];
  __shared__ short Bs[128 * 32];
  const int tid = threadIdx.x;
  const int lane = tid & 63;
  const int w = tid >> 6;
  const int g = lane >> 4, c = lane & 15;
  const int m0 = blockIdx.y * 128, n0 = blockIdx.x * 128;
  const int wm = (w >> 1) * 64, wn = (w & 1) * 64;
  f32x4 acc[4][4] = {};
  const int p0 = tid, p1 = tid + 256;
  const int rowA0 = p0 >> 2, logA0 = (p0 & 3) ^ ((p0 >> 3) & 3);
  const int rowA1 = p1 >> 2, logA1 = (p1 & 3) ^ ((p1 >> 3) & 3);
  const short* a0 = A + (size_t)(m0 + rowA0) * 1024 + logA0 * 8;
  const short* a1 = A + (size_t)(m0 + rowA1) * 1024 + logA1 * 8;
  const short* b0 = B + (size_t)(n0 + rowA0) * 1024 + logA0 * 8;
  const short* b1 = B + (size_t)(n0 + rowA1) * 1024 + logA1 * 8;
  short* lA0 = As + p0 * 8; short* lA1 = As + p1 * 8;
  short* lB0 = Bs + p0 * 8; short* lB1 = Bs + p1 * 8;

  for (int k0 = 0; k0 < 1024; k0 += 32) {
    gl_lds16(a0 + k0, lA0);
    gl_lds16(a1 + k0, lA1);
    gl_lds16(b0 + k0, lB0);
    gl_lds16(b1 + k0, lB1);
    __syncthreads();
    bf16x8 af[4], bfr[4];
#pragma unroll
    for (int t = 0; t < 4; t++) {
      int ra = wm + t * 16 + c;
      af[t] = *(const bf16x8*)(As + ra * 32 + (g ^ ((ra >> 1) & 3)) * 8);
      int rb = wn + t * 16 + c;
      bfr[t] = *(const bf16x8*)(Bs + rb * 32 + (g ^ ((rb >> 1) & 3)) * 8);
    }
#pragma unroll
    for (int i = 0; i < 4; i++)
#pragma unroll
      for (int jn = 0; jn < 4; jn++)
        acc[i][jn] = __builtin_amdgcn_mfma_f32_16x16x32_bf16(af[i], bfr[jn], acc[i][jn], 0, 0, 0);
    __syncthreads();
  }

  const int which = n0 >> 10;  // block-uniform: 0=Q 1=K 2=V
  const float qscale = 0.125f * 1.4426950408889634f;
  if (which == 2) {
#pragma unroll
    for (int jn = 0; jn < 4; jn++) {
      const int col = n0 + wn + jn * 16 + c;
      const float bv = bias[col];
      const int cw = col & 1023;
      const int h = cw >> 6, d = cw & 63;
#pragma unroll
      for (int i = 0; i < 4; i++) {
        const int row = m0 + wm + i * 16 + g * 4;
        const int bb = row >> 11, l0 = row & 2047;
        int lo = pk2bf(acc[i][jn][0] + bv, acc[i][jn][1] + bv);
        int hi = pk2bf(acc[i][jn][2] + bv, acc[i][jn][3] + bv);
        *(int2*)(vtb + (size_t)((bb * 16 + h) * 64 + d) * 2048 + l0) = make_int2(lo, hi);
      }
    }
  } else {
    short* dst = (which == 0) ? qb : kb;
    const float sc = (which == 0) ? qscale : 1.0f;
#pragma unroll
    for (int jn = 0; jn < 4; jn++) {
      const int col = n0 + wn + jn * 16 + c;
      const float bv = bias[col];
      const int cw = col & 1023;
      const int h = cw >> 6, d = cw & 63;
#pragma unroll
      for (int i = 0; i < 4; i++) {
#pragma unroll
        for (int r = 0; r < 4; r++) {
          const int row = m0 + wm + i * 16 + g * 4 + r;
          const int bb = row >> 11, l = row & 2047;
          dst[((size_t)((bb * 16 + h) * 2048 + l) << 6) + d] = (short)f2bf((acc[i][jn][r] + bv) * sc);
        }
      }
    }
  }
}

// stage one 128-key K tile + V^T tile into LDS (async, all 512 threads)
__device__ __forceinline__ void stage_kv512(const short* __restrict__ Kt,
                                            const short* __restrict__ Vtt,
                                            short* ksb, short* vsb, int tid) {
#pragma unroll
  for (int t = 0; t < 2; t++) {
    int p = tid + t * 512;
    int krow = p >> 3, kchk = (p & 7) ^ (krow & 7);
    gl_lds16(Kt + (size_t)krow * 64 + kchk * 8, ksb + p * 8);
    int dv = p >> 4, vchk = (p & 15) ^ (dv & 15);
    gl_lds16(Vtt + (size_t)dv * 2048 + vchk * 8, vsb + p * 8);
  }
}

// ---------- flash attention (S^T form, dual-tile 512-thread blocks) ----------
// One block = (bh, pr): waves 0-3 compute query tile qt=15-pr, waves 4-7 qt=pr,
// SHARING one double-buffered K/V stream of (16-pr) tiles.
// __launch_bounds__(512, 2): per-wave reg cap 256 (round-3 allocation, no spill);
// at ~112 VGPR the HW fits 16 waves/CU and LDS (64 KB) allows the 2 blocks/CU.
// Grid 512 blocks x 8 waves = 4096 waves = exactly 16/CU full residency.
__global__ __launch_bounds__(512, 2) void k_attn(const short* __restrict__ Q,
                                                 const short* __restrict__ K,
                                                 const short* __restrict__ Vt,
                                                 short* __restrict__ O) {
  __shared__ short Ks[2][128 * 64];  // 2x16 KB [key][d], 8-chunk XOR swizzle
  __shared__ short Vs[2][64 * 128];  // 2x16 KB [d][key], 16-chunk XOR swizzle
  const int tid = threadIdx.x;       // 0..511
  const int lane = tid & 63;
  const int w = tid >> 6;            // 0..7
  const int wq = w & 3;              // 32-query sub-tile within the wave's query tile
  const int quad = lane >> 4, cq = lane & 15;
  const int bh = blockIdx.y;
  const int bb = bh >> 4, h = bh & 15;
  const size_t base = (size_t)bh * (2048 * 64);
  const int pr = blockIdx.x;         // 0..7
  const int myqt = (w < 4) ? (15 - pr) : pr;  // wave's query tile
  const int jmax = 15 - pr;          // last KV tile streamed by this block
  const int m0 = myqt * 128;
  const int sA = cq | (((2 * quad) & 3) << 4);
  const int sB = cq | (((2 * quad + 1) & 3) << 4);

  // Q B-frags straight from global (16B/lane)
  bf16x8 qf[2][2];
#pragma unroll
  for (int mt = 0; mt < 2; mt++)
#pragma unroll
    for (int kd = 0; kd < 2; kd++)
      qf[mt][kd] = *(const bf16x8*)(Q + base +
          (size_t)(m0 + wq * 32 + mt * 16 + cq) * 64 + (kd * 4 + quad) * 8);

  stage_kv512(K + base, Vt + base, Ks[0], Vs[0], tid);

  f32x4 o[2][4] = {};
  float m_run[2] = {-1e30f, -1e30f};
  float l_run[2] = {0.f, 0.f};

  for (int j = 0; j <= jmax; j++) {
    const int cur = j & 1;
    __syncthreads();  // buf[cur] staged; buf[cur^1] fully consumed
    if (j < jmax)
      stage_kv512(K + base + (size_t)(j + 1) * 128 * 64, Vt + base + (j + 1) * 128,
                  Ks[cur ^ 1], Vs[cur ^ 1], tid);
    if (j <= myqt) {  // wave-uniform guard
      const short* ks = Ks[cur];
      const short* vs = Vs[cur];

      // S^T[key][q] : per wave 128 keys x 32 queries
      f32x4 s[2][8] = {};
#pragma unroll
      for (int kd = 0; kd < 2; kd++)
#pragma unroll
        for (int nt = 0; nt < 8; nt++) {
          int krow = nt * 16 + cq;
          bf16x8 kf = *(const bf16x8*)(ks + krow * 64 + ((kd * 4 + quad) ^ (krow & 7)) * 8);
          s[0][nt] = __builtin_amdgcn_mfma_f32_16x16x32_bf16(kf, qf[0][kd], s[0][nt], 0, 0, 0);
          s[1][nt] = __builtin_amdgcn_mfma_f32_16x16x32_bf16(kf, qf[1][kd], s[1][nt], 0, 0, 0);
        }

      const bool diag = (j == myqt);
      bf16x8 pf[2][4];
#pragma unroll
      for (int mt = 0; mt < 2; mt++) {
        float mx = -1e30f;
        if (diag) {
          int qloc = wq * 32 + mt * 16 + cq;
#pragma unroll
          for (int nt = 0; nt < 8; nt++)
#pragma unroll
            for (int r = 0; r < 4; r++) {
              float v = (nt * 16 + quad * 4 + r > qloc) ? -1e30f : s[mt][nt][r];
              s[mt][nt][r] = v;
              mx = fmaxf(mx, v);
            }
        } else {
#pragma unroll
          for (int nt = 0; nt < 8; nt++)
#pragma unroll
            for (int r = 0; r < 4; r++) mx = fmaxf(mx, s[mt][nt][r]);
        }
        mx = fmaxf(mx, __shfl_xor(mx, 16));
        mx = fmaxf(mx, __shfl_xor(mx, 32));
        const float mn = fmaxf(m_run[mt], mx);
        const float alpha = fexp2(m_run[mt] - mn);
        m_run[mt] = mn;
        float lt = 0.f;
#pragma unroll
        for (int nt = 0; nt < 8; nt++)
#pragma unroll
          for (int r = 0; r < 4; r++) {
            float p = fexp2(s[mt][nt][r] - mn);
            s[mt][nt][r] = p;
            lt += p;
          }
        l_run[mt] = l_run[mt] * alpha + lt;
#pragma unroll
        for (int dn = 0; dn < 4; dn++) o[mt][dn] *= alpha;
        // P^T (C-layout) -> PV B-frag: pack pairs, route across quads
#pragma unroll
        for (int kt = 0; kt < 4; kt++) {
          int dA0 = pk2bf(s[mt][2 * kt][0], s[mt][2 * kt][1]);
          int dA1 = pk2bf(s[mt][2 * kt][2], s[mt][2 * kt][3]);
          int dB0 = pk2bf(s[mt][2 * kt + 1][0], s[mt][2 * kt + 1][1]);
          int dB1 = pk2bf(s[mt][2 * kt + 1][2], s[mt][2 * kt + 1][3]);
          i32x4 ow;
          {
            int t0 = __shfl(dA0, sA, 64), t1 = __shfl(dB0, sA, 64);
            ow[0] = (quad < 2) ? t0 : t1;
          }
          {
            int t0 = __shfl(dA1, sA, 64), t1 = __shfl(dB1, sA, 64);
            ow[1] = (quad < 2) ? t0 : t1;
          }
          {
            int t0 = __shfl(dA0, sB, 64), t1 = __shfl(dB0, sB, 64);
            ow[2] = (quad < 2) ? t0 : t1;
          }
          {
            int t0 = __shfl(dA1, sB, 64), t1 = __shfl(dB1, sB, 64);
            ow[3] = (quad < 2) ? t0 : t1;
          }
          pf[mt][kt] = __builtin_bit_cast(bf16x8, ow);
        }
      }

      // O^T += Vt * P  (A=Vt frag, B=P frag)
#pragma unroll
      for (int kt = 0; kt < 4; kt++)
#pragma unroll
        for (int dn = 0; dn < 4; dn++) {
          int drow = dn * 16 + cq;
          bf16x8 vtf = *(const bf16x8*)(vs + drow * 128 + ((kt * 4 + quad) ^ (drow & 15)) * 8);
          o[0][dn] = __builtin_amdgcn_mfma_f32_16x16x32_bf16(vtf, pf[0][kt], o[0][dn], 0, 0, 0);
          o[1][dn] = __builtin_amdgcn_mfma_f32_16x16x32_bf16(vtf, pf[1][kt], o[1][dn], 0, 0, 0);
        }
    }
  }

  // epilogue: reduce l across quads, normalize, pack 4 consecutive d -> 8B store
#pragma unroll
  for (int mt = 0; mt < 2; mt++) {
    float lf = l_run[mt];
    lf += __shfl_xor(lf, 16);
    lf += __shfl_xor(lf, 32);
    const float inv = 1.f / lf;
    const size_t rb = ((size_t)(bb * 2048 + m0 + wq * 32 + mt * 16 + cq)) * 1024 + h * 64;
#pragma unroll
    for (int dn = 0; dn < 4; dn++) {
      int d0 = pk2bf(o[mt][dn][0] * inv, o[mt][dn][1] * inv);
      int d1 = pk2bf(o[mt][dn][2] * inv, o[mt][dn][3] * inv);
      *(int2*)(O + rb + dn * 16 + quad * 4) = make_int2(d0, d1);
    }
  }
}

// ---------- out GEMM (BK=32): out[8192,1024] = AO @ WoutT^T + b (fp32 out) ----------
__global__ __launch_bounds__(256) void k_out_gemm(const short* __restrict__ A,
                                                  const short* __restrict__ B,
                                                  const float* __restrict__ bias,
                                                  float* __restrict__ out) {
  __shared__ short As[128 * 32];
  __shared__ short Bs[128 * 32];
  const int tid = threadIdx.x;
  const int lane = tid & 63;
  const int w = tid >> 6;
  const int g = lane >> 4, c = lane & 15;
  const int m0 = blockIdx.y * 128, n0 = blockIdx.x * 128;
  const int wm = (w >> 1) * 64, wn = (w & 1) * 64;
  f32x4 acc[4][4] = {};
  const int p0 = tid, p1 = tid + 256;
  const int rowA0 = p0 >> 2, logA0 = (p0 & 3) ^ ((p0 >> 3) & 3);
  const int rowA1 = p1 >> 2, logA1 = (p1 & 3) ^ ((p1 >> 3) & 3);
  const short* a0 = A + (size_t)(m0 + rowA0) * 1024 + logA0 * 8;
  const short* a1 = A + (size_t)(m0 + rowA1) * 1024 + logA1 * 8;
  const short* b0 = B + (size_t)(n0 + rowA0) * 1024 + logA0 * 8;
  const short* b1 = B + (size_t)(n0 + rowA1) * 1024 + logA1 * 8;
  short* lA0 = As + p0 * 8; short* lA1 = As + p1 * 8;
  short* lB0 = Bs + p0 * 8; short* lB1 = Bs + p1 * 8;

  for (int k0 = 0; k0 < 1024; k0 += 32) {
    gl_lds16(a0 + k0, lA0);
    gl_lds16(a1 + k0, lA1);
    gl_lds16(b0 + k0, lB0);
    gl_lds16(b1 + k0, lB1);
    __syncthreads();
    bf16x8 af[4], bfr[4];
#pragma unroll
    for (int t = 0; t < 4; t++) {
      int ra = wm + t * 16 + c;
      af[t] = *(const bf16x8*)(As + ra * 32 + (g ^ ((ra >> 1) & 3)) * 8);
      int rb = wn + t * 16 + c;
      bfr[t] = *(const bf16x8*)(Bs + rb * 32 + (g ^ ((rb >> 1) & 3)) * 8);
    }
#pragma unroll
    for (int i = 0; i < 4; i++)
#pragma unroll
      for (int jn = 0; jn < 4; jn++)
        acc[i][jn] = __builtin_amdgcn_mfma_f32_16x16x32_bf16(af[i], bfr[jn], acc[i][jn], 0, 0, 0);
    __syncthreads();
  }
#pragma unroll
  for (int jn = 0; jn < 4; jn++) {
    const int col = n0 + wn + jn * 16 + c;
    const float bv = bias[col];
#pragma unroll
    for (int i = 0; i < 4; i++) {
#pragma unroll
      for (int r = 0; r < 4; r++) {
        const int row = m0 + wm + i * 16 + g * 4 + r;
        out[(size_t)row * 1024 + col] = acc[i][jn][r] + bv;
      }
    }
  }
}

// ---------- launch ----------
extern "C" void kernel_launch(void* const* d_in, const int* in_sizes, int n_in,
                              void* d_out, int out_size, void* d_ws, size_t ws_size,
                              hipStream_t stream) {
  const float* x     = (const float*)d_in[0];
  const float* w_in  = (const float*)d_in[1];
  const float* b_in  = (const float*)d_in[2];
  const float* w_out = (const float*)d_in[3];
  const float* b_out = (const float*)d_in[4];
  float* out = (float*)d_out;
  char* ws = (char*)d_ws;
  short* x_bf   = (short*)(ws);                      // 16 MB  [8192,1024] bf16
  short* w_inT  = (short*)(ws + (16ull << 20));      //  6 MB  [3072,1024] bf16
  short* w_outT = (short*)(ws + (22ull << 20));      //  2 MB  [1024,1024] bf16
  short* qb     = (short*)(ws + (24ull << 20));      // 16 MB  [B,H,L,64]  bf16 (pre-scaled)
  short* kb     = (short*)(ws + (40ull << 20));      // 16 MB  [B,H,L,64]  bf16
  short* vtb    = (short*)(ws + (56ull << 20));      // 16 MB  [B,H,64,L]  bf16
  short* ao     = (short*)(ws + (72ull << 20));      // 16 MB  [B,L,H*64]  bf16

  k_convert_x<<<dim3(4096), dim3(256), 0, stream>>>(x, x_bf);
  k_transpose_cvt<<<dim3(96, 32), dim3(32, 8), 0, stream>>>(w_in, w_inT, 1024, 3072);
  k_transpose_cvt<<<dim3(32, 32), dim3(32, 8), 0, stream>>>(w_out, w_outT, 1024, 1024);
  k_qkv_gemm<<<dim3(24, 64), dim3(256), 0, stream>>>(x_bf, w_inT, b_in, qb, kb, vtb);
  k_attn<<<dim3(8, 64), dim3(512), 0, stream>>>(qb, kb, vtb, ao);
  k_out_gemm<<<dim3(8, 64), dim3(256), 0, stream>>>(ao, w_outT, b_out, out);
}

// Round 7
// 288.710 us; speedup vs baseline: 1.4485x; 1.0218x over previous
//
#include <hip/hip_runtime.h>

// ---------- types ----------
typedef float f32x4 __attribute__((ext_vector_type(4)));
typedef __bf16 bf16x8 __attribute__((ext_vector_type(8)));
typedef short s16x8 __attribute__((ext_vector_type(8)));
typedef int i32x4 __attribute__((ext_vector_type(4)));

// f32 -> bf16 round-to-nearest-even
__device__ __forceinline__ unsigned short f2bf(float f) {
  union { float f; unsigned u; } v;
  v.f = f;
  unsigned r = v.u + 0x7FFFu + ((v.u >> 16) & 1u);
  return (unsigned short)(r >> 16);
}

// pack two f32 -> packed bf16x2 (round-half-up via +0x8000, then byte-perm)
__device__ __forceinline__ int pk2bf(float lo, float hi) {
  unsigned a = __builtin_bit_cast(unsigned, lo) + 0x8000u;
  unsigned b = __builtin_bit_cast(unsigned, hi) + 0x8000u;
  return (int)__builtin_amdgcn_perm(b, a, 0x07060302u);
}

#if __has_builtin(__builtin_amdgcn_exp2f)
__device__ __forceinline__ float fexp2(float x) { return __builtin_amdgcn_exp2f(x); }
#else
__device__ __forceinline__ float fexp2(float x) { return exp2f(x); }
#endif

// async 16B global->LDS (wave-uniform base + lane*16; our mappings respect this)
__device__ __forceinline__ void gl_lds16(const void* g, void* l) {
  __builtin_amdgcn_global_load_lds(
      (__attribute__((address_space(1))) void*)g,
      (__attribute__((address_space(3))) void*)l, 16, 0, 0);
}

// ---------- pre-pass kernels ----------
__global__ __launch_bounds__(256) void k_convert_x(const float* __restrict__ in,
                                                   short* __restrict__ out) {
  int i = (blockIdx.x * 256 + threadIdx.x) * 8;
  const float4* p = (const float4*)(in + i);
  float4 a = p[0], b = p[1];
  s16x8 r;
  r[0] = (short)f2bf(a.x); r[1] = (short)f2bf(a.y);
  r[2] = (short)f2bf(a.z); r[3] = (short)f2bf(a.w);
  r[4] = (short)f2bf(b.x); r[5] = (short)f2bf(b.y);
  r[6] = (short)f2bf(b.z); r[7] = (short)f2bf(b.w);
  *(s16x8*)(out + i) = r;
}

// in: [R,C] f32 row-major -> out: [C,R] bf16 row-major
__global__ __launch_bounds__(256) void k_transpose_cvt(const float* __restrict__ in,
                                                       short* __restrict__ out,
                                                       int R, int C) {
  __shared__ short tile[32][33];
  int c0 = blockIdx.x * 32, r0 = blockIdx.y * 32;
  int tx = threadIdx.x, ty = threadIdx.y;
#pragma unroll
  for (int i = 0; i < 32; i += 8)
    tile[ty + i][tx] = (short)f2bf(in[(size_t)(r0 + ty + i) * C + c0 + tx]);
  __syncthreads();
#pragma unroll
  for (int i = 0; i < 32; i += 8)
    out[(size_t)(c0 + ty + i) * R + r0 + tx] = tile[tx][ty + i];
}

// ---------- QKV GEMM (BK=32): C[8192,3072] = Xbf @ WinT^T + b ----------
__global__ __launch_bounds__(256) void k_qkv_gemm(const short* __restrict__ A,
                                                  const short* __restrict__ B,
                                                  const float* __restrict__ bias,
                                                  short* __restrict__ qb,
                                                  short* __restrict__ kb,
                                                  short* __restrict__ vtb) {
  __shared__ short As[128 * 32];
  __shared__ short Bs[128 * 32];
  const int tid = threadIdx.x;
  const int lane = tid & 63;
  const int w = tid >> 6;
  const int g = lane >> 4, c = lane & 15;
  const int m0 = blockIdx.y * 128, n0 = blockIdx.x * 128;
  const int wm = (w >> 1) * 64, wn = (w & 1) * 64;
  f32x4 acc[4][4] = {};
  const int p0 = tid, p1 = tid + 256;
  const int rowA0 = p0 >> 2, logA0 = (p0 & 3) ^ ((p0 >> 3) & 3);
  const int rowA1 = p1 >> 2, logA1 = (p1 & 3) ^ ((p1 >> 3) & 3);
  const short* a0 = A + (size_t)(m0 + rowA0) * 1024 + logA0 * 8;
  const short* a1 = A + (size_t)(m0 + rowA1) * 1024 + logA1 * 8;
  const short* b0 = B + (size_t)(n0 + rowA0) * 1024 + logA0 * 8;
  const short* b1 = B + (size_t)(n0 + rowA1) * 1024 + logA1 * 8;
  short* lA0 = As + p0 * 8; short* lA1 = As + p1 * 8;
  short* lB0 = Bs + p0 * 8; short* lB1 = Bs + p1 * 8;

  for (int k0 = 0; k0 < 1024; k0 += 32) {
    gl_lds16(a0 + k0, lA0);
    gl_lds16(a1 + k0, lA1);
    gl_lds16(b0 + k0, lB0);
    gl_lds16(b1 + k0, lB1);
    __syncthreads();
    bf16x8 af[4], bfr[4];
#pragma unroll
    for (int t = 0; t < 4; t++) {
      int ra = wm + t * 16 + c;
      af[t] = *(const bf16x8*)(As + ra * 32 + (g ^ ((ra >> 1) & 3)) * 8);
      int rb = wn + t * 16 + c;
      bfr[t] = *(const bf16x8*)(Bs + rb * 32 + (g ^ ((rb >> 1) & 3)) * 8);
    }
#pragma unroll
    for (int i = 0; i < 4; i++)
#pragma unroll
      for (int jn = 0; jn < 4; jn++)
        acc[i][jn] = __builtin_amdgcn_mfma_f32_16x16x32_bf16(af[i], bfr[jn], acc[i][jn], 0, 0, 0);
    __syncthreads();
  }

  const int which = n0 >> 10;  // block-uniform: 0=Q 1=K 2=V
  const float qscale = 0.125f * 1.4426950408889634f;
  if (which == 2) {
#pragma unroll
    for (int jn = 0; jn < 4; jn++) {
      const int col = n0 + wn + jn * 16 + c;
      const float bv = bias[col];
      const int cw = col & 1023;
      const int h = cw >> 6, d = cw & 63;
#pragma unroll
      for (int i = 0; i < 4; i++) {
        const int row = m0 + wm + i * 16 + g * 4;
        const int bb = row >> 11, l0 = row & 2047;
        int lo = pk2bf(acc[i][jn][0] + bv, acc[i][jn][1] + bv);
        int hi = pk2bf(acc[i][jn][2] + bv, acc[i][jn][3] + bv);
        *(int2*)(vtb + (size_t)((bb * 16 + h) * 64 + d) * 2048 + l0) = make_int2(lo, hi);
      }
    }
  } else {
    short* dst = (which == 0) ? qb : kb;
    const float sc = (which == 0) ? qscale : 1.0f;
#pragma unroll
    for (int jn = 0; jn < 4; jn++) {
      const int col = n0 + wn + jn * 16 + c;
      const float bv = bias[col];
      const int cw = col & 1023;
      const int h = cw >> 6, d = cw & 63;
#pragma unroll
      for (int i = 0; i < 4; i++) {
#pragma unroll
        for (int r = 0; r < 4; r++) {
          const int row = m0 + wm + i * 16 + g * 4 + r;
          const int bb = row >> 11, l = row & 2047;
          dst[((size_t)((bb * 16 + h) * 2048 + l) << 6) + d] = (short)f2bf((acc[i][jn][r] + bv) * sc);
        }
      }
    }
  }
}

// stage one 128-key K tile + V^T tile into LDS (async, all 512 threads)
__device__ __forceinline__ void stage_kv512(const short* __restrict__ Kt,
                                            const short* __restrict__ Vtt,
                                            short* ksb, short* vsb, int tid) {
#pragma unroll
  for (int t = 0; t < 2; t++) {
    int p = tid + t * 512;
    int krow = p >> 3, kchk = (p & 7) ^ (krow & 7);
    gl_lds16(Kt + (size_t)krow * 64 + kchk * 8, ksb + p * 8);
    int dv = p >> 4, vchk = (p & 15) ^ (dv & 15);
    gl_lds16(Vtt + (size_t)dv * 2048 + vchk * 8, vsb + p * 8);
  }
}

// ---------- flash attention (S^T form, balanced split-slice 512-thread blocks) ----------
// Block (bh, pr): 8 waves. Wave w owns TWO 16-query slices: slice w of tile
// qhi=15-pr (mt0) and slice w of tile qlo=pr (mt1), sharing one double-buffered
// KV stream of (16-pr) tiles. Per step j: mt0 always computes, mt1 only for
// j<=qlo. Per-wave work = (16-pr)+(pr+1) = 17 mt-units for EVERY wave of EVERY
// block -- zero wave idle (fixes round-6's ~33% idle slots), 16 waves/CU.
__global__ __launch_bounds__(512, 2) void k_attn(const short* __restrict__ Q,
                                                 const short* __restrict__ K,
                                                 const short* __restrict__ Vt,
                                                 short* __restrict__ O) {
  __shared__ short Ks[2][128 * 64];  // 2x16 KB [key][d], 8-chunk XOR swizzle
  __shared__ short Vs[2][64 * 128];  // 2x16 KB [d][key], 16-chunk XOR swizzle
  const int tid = threadIdx.x;       // 0..511
  const int lane = tid & 63;
  const int w = tid >> 6;            // 0..7 : 16-query slice index within each tile
  const int quad = lane >> 4, cq = lane & 15;
  const int bh = blockIdx.y;
  const int bb = bh >> 4, h = bh & 15;
  const size_t base = (size_t)bh * (2048 * 64);
  const int pr = blockIdx.x;         // 0..7
  const int qhi = 15 - pr, qlo = pr;
  const int jmax = qhi;
  const int sA = cq | (((2 * quad) & 3) << 4);
  const int sB = cq | (((2 * quad + 1) & 3) << 4);
  const int qloc = w * 16 + cq;      // within-tile query row (same for both slices)

  // Q B-frags straight from global (16B/lane): mt0 -> tile qhi, mt1 -> tile qlo
  bf16x8 qf[2][2];
#pragma unroll
  for (int mt = 0; mt < 2; mt++) {
    const int qt = mt ? qlo : qhi;
#pragma unroll
    for (int kd = 0; kd < 2; kd++)
      qf[mt][kd] = *(const bf16x8*)(Q + base +
          (size_t)(qt * 128 + w * 16 + cq) * 64 + (kd * 4 + quad) * 8);
  }

  stage_kv512(K + base, Vt + base, Ks[0], Vs[0], tid);

  f32x4 o[2][4] = {};
  float m_run[2] = {-1e30f, -1e30f};
  float l_run[2] = {0.f, 0.f};

  for (int j = 0; j <= jmax; j++) {
    const int cur = j & 1;
    __syncthreads();  // buf[cur] staged; buf[cur^1] fully consumed
    if (j < jmax)
      stage_kv512(K + base + (size_t)(j + 1) * 128 * 64, Vt + base + (j + 1) * 128,
                  Ks[cur ^ 1], Vs[cur ^ 1], tid);
    const short* ks = Ks[cur];
    const short* vs = Vs[cur];
    const bool act1 = (j <= qlo);  // block-uniform

    // S^T[key][q] : 128 keys x 16 queries per active slice (K-frags shared)
    f32x4 s[2][8] = {};
    if (act1) {
#pragma unroll
      for (int kd = 0; kd < 2; kd++)
#pragma unroll
        for (int nt = 0; nt < 8; nt++) {
          int krow = nt * 16 + cq;
          bf16x8 kf = *(const bf16x8*)(ks + krow * 64 + ((kd * 4 + quad) ^ (krow & 7)) * 8);
          s[0][nt] = __builtin_amdgcn_mfma_f32_16x16x32_bf16(kf, qf[0][kd], s[0][nt], 0, 0, 0);
          s[1][nt] = __builtin_amdgcn_mfma_f32_16x16x32_bf16(kf, qf[1][kd], s[1][nt], 0, 0, 0);
        }
    } else {
#pragma unroll
      for (int kd = 0; kd < 2; kd++)
#pragma unroll
        for (int nt = 0; nt < 8; nt++) {
          int krow = nt * 16 + cq;
          bf16x8 kf = *(const bf16x8*)(ks + krow * 64 + ((kd * 4 + quad) ^ (krow & 7)) * 8);
          s[0][nt] = __builtin_amdgcn_mfma_f32_16x16x32_bf16(kf, qf[0][kd], s[0][nt], 0, 0, 0);
        }
    }

    bf16x8 pf[2][4];
    const int nmt = act1 ? 2 : 1;
#pragma unroll
    for (int mt = 0; mt < 2; mt++) {
      if (mt >= nmt) break;  // block-uniform
      const bool diag = (j == (mt ? qlo : qhi));
      float mx = -1e30f;
      if (diag) {
#pragma unroll
        for (int nt = 0; nt < 8; nt++)
#pragma unroll
          for (int r = 0; r < 4; r++) {
            float v = (nt * 16 + quad * 4 + r > qloc) ? -1e30f : s[mt][nt][r];
            s[mt][nt][r] = v;
            mx = fmaxf(mx, v);
          }
      } else {
#pragma unroll
        for (int nt = 0; nt < 8; nt++)
#pragma unroll
          for (int r = 0; r < 4; r++) mx = fmaxf(mx, s[mt][nt][r]);
      }
      mx = fmaxf(mx, __shfl_xor(mx, 16));
      mx = fmaxf(mx, __shfl_xor(mx, 32));
      const float mn = fmaxf(m_run[mt], mx);
      const float alpha = fexp2(m_run[mt] - mn);
      m_run[mt] = mn;
      float lt = 0.f;
#pragma unroll
      for (int nt = 0; nt < 8; nt++)
#pragma unroll
        for (int r = 0; r < 4; r++) {
          float p = fexp2(s[mt][nt][r] - mn);
          s[mt][nt][r] = p;
          lt += p;
        }
      l_run[mt] = l_run[mt] * alpha + lt;
#pragma unroll
      for (int dn = 0; dn < 4; dn++) o[mt][dn] *= alpha;
      // P^T (C-layout) -> PV B-frag: pack pairs, route across quads
#pragma unroll
      for (int kt = 0; kt < 4; kt++) {
        int dA0 = pk2bf(s[mt][2 * kt][0], s[mt][2 * kt][1]);
        int dA1 = pk2bf(s[mt][2 * kt][2], s[mt][2 * kt][3]);
        int dB0 = pk2bf(s[mt][2 * kt + 1][0], s[mt][2 * kt + 1][1]);
        int dB1 = pk2bf(s[mt][2 * kt + 1][2], s[mt][2 * kt + 1][3]);
        i32x4 ow;
        {
          int t0 = __shfl(dA0, sA, 64), t1 = __shfl(dB0, sA, 64);
          ow[0] = (quad < 2) ? t0 : t1;
        }
        {
          int t0 = __shfl(dA1, sA, 64), t1 = __shfl(dB1, sA, 64);
          ow[1] = (quad < 2) ? t0 : t1;
        }
        {
          int t0 = __shfl(dA0, sB, 64), t1 = __shfl(dB0, sB, 64);
          ow[2] = (quad < 2) ? t0 : t1;
        }
        {
          int t0 = __shfl(dA1, sB, 64), t1 = __shfl(dB1, sB, 64);
          ow[3] = (quad < 2) ? t0 : t1;
        }
        pf[mt][kt] = __builtin_bit_cast(bf16x8, ow);
      }
    }

    // O^T += Vt * P  (V-frags shared across active slices)
    if (act1) {
#pragma unroll
      for (int kt = 0; kt < 4; kt++)
#pragma unroll
        for (int dn = 0; dn < 4; dn++) {
          int drow = dn * 16 + cq;
          bf16x8 vtf = *(const bf16x8*)(vs + drow * 128 + ((kt * 4 + quad) ^ (drow & 15)) * 8);
          o[0][dn] = __builtin_amdgcn_mfma_f32_16x16x32_bf16(vtf, pf[0][kt], o[0][dn], 0, 0, 0);
          o[1][dn] = __builtin_amdgcn_mfma_f32_16x16x32_bf16(vtf, pf[1][kt], o[1][dn], 0, 0, 0);
        }
    } else {
#pragma unroll
      for (int kt = 0; kt < 4; kt++)
#pragma unroll
        for (int dn = 0; dn < 4; dn++) {
          int drow = dn * 16 + cq;
          bf16x8 vtf = *(const bf16x8*)(vs + drow * 128 + ((kt * 4 + quad) ^ (drow & 15)) * 8);
          o[0][dn] = __builtin_amdgcn_mfma_f32_16x16x32_bf16(vtf, pf[0][kt], o[0][dn], 0, 0, 0);
        }
    }
  }

  // epilogue: reduce l across quads, normalize, pack 4 consecutive d -> 8B store
#pragma unroll
  for (int mt = 0; mt < 2; mt++) {
    const int qt = mt ? qlo : qhi;
    float lf = l_run[mt];
    lf += __shfl_xor(lf, 16);
    lf += __shfl_xor(lf, 32);
    const float inv = 1.f / lf;
    const size_t rb = ((size_t)(bb * 2048 + qt * 128 + w * 16 + cq)) * 1024 + h * 64;
#pragma unroll
    for (int dn = 0; dn < 4; dn++) {
      int d0 = pk2bf(o[mt][dn][0] * inv, o[mt][dn][1] * inv);
      int d1 = pk2bf(o[mt][dn][2] * inv, o[mt][dn][3] * inv);
      *(int2*)(O + rb + dn * 16 + quad * 4) = make_int2(d0, d1);
    }
  }
}

// ---------- out GEMM (BK=32): out[8192,1024] = AO @ WoutT^T + b (fp32 out) ----------
__global__ __launch_bounds__(256) void k_out_gemm(const short* __restrict__ A,
                                                  const short* __restrict__ B,
                                                  const float* __restrict__ bias,
                                                  float* __restrict__ out) {
  __shared__ short As[128 * 32];
  __shared__ short Bs[128 * 32];
  const int tid = threadIdx.x;
  const int lane = tid & 63;
  const int w = tid >> 6;
  const int g = lane >> 4, c = lane & 15;
  const int m0 = blockIdx.y * 128, n0 = blockIdx.x * 128;
  const int wm = (w >> 1) * 64, wn = (w & 1) * 64;
  f32x4 acc[4][4] = {};
  const int p0 = tid, p1 = tid + 256;
  const int rowA0 = p0 >> 2, logA0 = (p0 & 3) ^ ((p0 >> 3) & 3);
  const int rowA1 = p1 >> 2, logA1 = (p1 & 3) ^ ((p1 >> 3) & 3);
  const short* a0 = A + (size_t)(m0 + rowA0) * 1024 + logA0 * 8;
  const short* a1 = A + (size_t)(m0 + rowA1) * 1024 + logA1 * 8;
  const short* b0 = B + (size_t)(n0 + rowA0) * 1024 + logA0 * 8;
  const short* b1 = B + (size_t)(n0 + rowA1) * 1024 + logA1 * 8;
  short* lA0 = As + p0 * 8; short* lA1 = As + p1 * 8;
  short* lB0 = Bs + p0 * 8; short* lB1 = Bs + p1 * 8;

  for (int k0 = 0; k0 < 1024; k0 += 32) {
    gl_lds16(a0 + k0, lA0);
    gl_lds16(a1 + k0, lA1);
    gl_lds16(b0 + k0, lB0);
    gl_lds16(b1 + k0, lB1);
    __syncthreads();
    bf16x8 af[4], bfr[4];
#pragma unroll
    for (int t = 0; t < 4; t++) {
      int ra = wm + t * 16 + c;
      af[t] = *(const bf16x8*)(As + ra * 32 + (g ^ ((ra >> 1) & 3)) * 8);
      int rb = wn + t * 16 + c;
      bfr[t] = *(const bf16x8*)(Bs + rb * 32 + (g ^ ((rb >> 1) & 3)) * 8);
    }
#pragma unroll
    for (int i = 0; i < 4; i++)
#pragma unroll
      for (int jn = 0; jn < 4; jn++)
        acc[i][jn] = __builtin_amdgcn_mfma_f32_16x16x32_bf16(af[i], bfr[jn], acc[i][jn], 0, 0, 0);
    __syncthreads();
  }
#pragma unroll
  for (int jn = 0; jn < 4; jn++) {
    const int col = n0 + wn + jn * 16 + c;
    const float bv = bias[col];
#pragma unroll
    for (int i = 0; i < 4; i++) {
#pragma unroll
      for (int r = 0; r < 4; r++) {
        const int row = m0 + wm + i * 16 + g * 4 + r;
        out[(size_t)row * 1024 + col] = acc[i][jn][r] + bv;
      }
    }
  }
}

// ---------- launch ----------
extern "C" void kernel_launch(void* const* d_in, const int* in_sizes, int n_in,
                              void* d_out, int out_size, void* d_ws, size_t ws_size,
                              hipStream_t stream) {
  const float* x     = (const float*)d_in[0];
  const float* w_in  = (const float*)d_in[1];
  const float* b_in  = (const float*)d_in[2];
  const float* w_out = (const float*)d_in[3];
  const float* b_out = (const float*)d_in[4];
  float* out = (float*)d_out;
  char* ws = (char*)d_ws;
  short* x_bf   = (short*)(ws);                      // 16 MB  [8192,1024] bf16
  short* w_inT  = (short*)(ws + (16ull << 20));      //  6 MB  [3072,1024] bf16
  short* w_outT = (short*)(ws + (22ull << 20));      //  2 MB  [1024,1024] bf16
  short* qb     = (short*)(ws + (24ull << 20));      // 16 MB  [B,H,L,64]  bf16 (pre-scaled)
  short* kb     = (short*)(ws + (40ull << 20));      // 16 MB  [B,H,L,64]  bf16
  short* vtb    = (short*)(ws + (56ull << 20));      // 16 MB  [B,H,64,L]  bf16
  short* ao     = (short*)(ws + (72ull << 20));      // 16 MB  [B,L,H*64]  bf16

  k_convert_x<<<dim3(4096), dim3(256), 0, stream>>>(x, x_bf);
  k_transpose_cvt<<<dim3(96, 32), dim3(32, 8), 0, stream>>>(w_in, w_inT, 1024, 3072);
  k_transpose_cvt<<<dim3(32, 32), dim3(32, 8), 0, stream>>>(w_out, w_outT, 1024, 1024);
  k_qkv_gemm<<<dim3(24, 64), dim3(256), 0, stream>>>(x_bf, w_inT, b_in, qb, kb, vtb);
  k_attn<<<dim3(8, 64), dim3(512), 0, stream>>>(qb, kb, vtb, ao);
  k_out_gemm<<<dim3(8, 64), dim3(256), 0, stream>>>(ao, w_outT, b_out, out);
}

// Round 8
// 276.686 us; speedup vs baseline: 1.5114x; 1.0435x over previous
//
#include <hip/hip_runtime.h>

// ---------- types ----------
typedef float f32x4 __attribute__((ext_vector_type(4)));
typedef __bf16 bf16x8 __attribute__((ext_vector_type(8)));
typedef short s16x8 __attribute__((ext_vector_type(8)));
typedef int i32x4 __attribute__((ext_vector_type(4)));

// f32 -> bf16 round-to-nearest-even
__device__ __forceinline__ unsigned short f2bf(float f) {
  union { float f; unsigned u; } v;
  v.f = f;
  unsigned r = v.u + 0x7FFFu + ((v.u >> 16) & 1u);
  return (unsigned short)(r >> 16);
}

// pack two f32 -> packed bf16x2 (round-half-up via +0x8000, then byte-perm)
__device__ __forceinline__ int pk2bf(float lo, float hi) {
  unsigned a = __builtin_bit_cast(unsigned, lo) + 0x8000u;
  unsigned b = __builtin_bit_cast(unsigned, hi) + 0x8000u;
  return (int)__builtin_amdgcn_perm(b, a, 0x07060302u);
}

#if __has_builtin(__builtin_amdgcn_exp2f)
__device__ __forceinline__ float fexp2(float x) { return __builtin_amdgcn_exp2f(x); }
#else
__device__ __forceinline__ float fexp2(float x) { return exp2f(x); }
#endif

// async 16B global->LDS (wave-uniform base + lane*16; our mappings respect this)
__device__ __forceinline__ void gl_lds16(const void* g, void* l) {
  __builtin_amdgcn_global_load_lds(
      (__attribute__((address_space(1))) void*)g,
      (__attribute__((address_space(3))) void*)l, 16, 0, 0);
}

// ---------- pre-pass kernels ----------
__global__ __launch_bounds__(256) void k_convert_x(const float* __restrict__ in,
                                                   short* __restrict__ out) {
  int i = (blockIdx.x * 256 + threadIdx.x) * 8;
  const float4* p = (const float4*)(in + i);
  float4 a = p[0], b = p[1];
  s16x8 r;
  r[0] = (short)f2bf(a.x); r[1] = (short)f2bf(a.y);
  r[2] = (short)f2bf(a.z); r[3] = (short)f2bf(a.w);
  r[4] = (short)f2bf(b.x); r[5] = (short)f2bf(b.y);
  r[6] = (short)f2bf(b.z); r[7] = (short)f2bf(b.w);
  *(s16x8*)(out + i) = r;
}

// in: [R,C] f32 row-major -> out: [C,R] bf16 row-major
__global__ __launch_bounds__(256) void k_transpose_cvt(const float* __restrict__ in,
                                                       short* __restrict__ out,
                                                       int R, int C) {
  __shared__ short tile[32][33];
  int c0 = blockIdx.x * 32, r0 = blockIdx.y * 32;
  int tx = threadIdx.x, ty = threadIdx.y;
#pragma unroll
  for (int i = 0; i < 32; i += 8)
    tile[ty + i][tx] = (short)f2bf(in[(size_t)(r0 + ty + i) * C + c0 + tx]);
  __syncthreads();
#pragma unroll
  for (int i = 0; i < 32; i += 8)
    out[(size_t)(c0 + ty + i) * R + r0 + tx] = tile[tx][ty + i];
}

// ---------- QKV GEMM (BK=32): C[8192,3072] = Xbf @ WinT^T + b ----------
__global__ __launch_bounds__(256) void k_qkv_gemm(const short* __restrict__ A,
                                                  const short* __restrict__ B,
                                                  const float* __restrict__ bias,
                                                  short* __restrict__ qb,
                                                  short* __restrict__ kb,
                                                  short* __restrict__ vtb) {
  __shared__ short As[128 * 32];
  __shared__ short Bs[128 * 32];
  const int tid = threadIdx.x;
  const int lane = tid & 63;
  const int w = tid >> 6;
  const int g = lane >> 4, c = lane & 15;
  const int m0 = blockIdx.y * 128, n0 = blockIdx.x * 128;
  const int wm = (w >> 1) * 64, wn = (w & 1) * 64;
  f32x4 acc[4][4] = {};
  const int p0 = tid, p1 = tid + 256;
  const int rowA0 = p0 >> 2, logA0 = (p0 & 3) ^ ((p0 >> 3) & 3);
  const int rowA1 = p1 >> 2, logA1 = (p1 & 3) ^ ((p1 >> 3) & 3);
  const short* a0 = A + (size_t)(m0 + rowA0) * 1024 + logA0 * 8;
  const short* a1 = A + (size_t)(m0 + rowA1) * 1024 + logA1 * 8;
  const short* b0 = B + (size_t)(n0 + rowA0) * 1024 + logA0 * 8;
  const short* b1 = B + (size_t)(n0 + rowA1) * 1024 + logA1 * 8;
  short* lA0 = As + p0 * 8; short* lA1 = As + p1 * 8;
  short* lB0 = Bs + p0 * 8; short* lB1 = Bs + p1 * 8;

  for (int k0 = 0; k0 < 1024; k0 += 32) {
    gl_lds16(a0 + k0, lA0);
    gl_lds16(a1 + k0, lA1);
    gl_lds16(b0 + k0, lB0);
    gl_lds16(b1 + k0, lB1);
    __syncthreads();
    bf16x8 af[4], bfr[4];
#pragma unroll
    for (int t = 0; t < 4; t++) {
      int ra = wm + t * 16 + c;
      af[t] = *(const bf16x8*)(As + ra * 32 + (g ^ ((ra >> 1) & 3)) * 8);
      int rb = wn + t * 16 + c;
      bfr[t] = *(const bf16x8*)(Bs + rb * 32 + (g ^ ((rb >> 1) & 3)) * 8);
    }
#pragma unroll
    for (int i = 0; i < 4; i++)
#pragma unroll
      for (int jn = 0; jn < 4; jn++)
        acc[i][jn] = __builtin_amdgcn_mfma_f32_16x16x32_bf16(af[i], bfr[jn], acc[i][jn], 0, 0, 0);
    __syncthreads();
  }

  const int which = n0 >> 10;  // block-uniform: 0=Q 1=K 2=V
  const float qscale = 0.125f * 1.4426950408889634f;
  if (which == 2) {
#pragma unroll
    for (int jn = 0; jn < 4; jn++) {
      const int col = n0 + wn + jn * 16 + c;
      const float bv = bias[col];
      const int cw = col & 1023;
      const int h = cw >> 6, d = cw & 63;
#pragma unroll
      for (int i = 0; i < 4; i++) {
        const int row = m0 + wm + i * 16 + g * 4;
        const int bb = row >> 11, l0 = row & 2047;
        int lo = pk2bf(acc[i][jn][0] + bv, acc[i][jn][1] + bv);
        int hi = pk2bf(acc[i][jn][2] + bv, acc[i][jn][3] + bv);
        *(int2*)(vtb + (size_t)((bb * 16 + h) * 64 + d) * 2048 + l0) = make_int2(lo, hi);
      }
    }
  } else {
    short* dst = (which == 0) ? qb : kb;
    const float sc = (which == 0) ? qscale : 1.0f;
#pragma unroll
    for (int jn = 0; jn < 4; jn++) {
      const int col = n0 + wn + jn * 16 + c;
      const float bv = bias[col];
      const int cw = col & 1023;
      const int h = cw >> 6, d = cw & 63;
#pragma unroll
      for (int i = 0; i < 4; i++) {
#pragma unroll
        for (int r = 0; r < 4; r++) {
          const int row = m0 + wm + i * 16 + g * 4 + r;
          const int bb = row >> 11, l = row & 2047;
          dst[((size_t)((bb * 16 + h) * 2048 + l) << 6) + d] = (short)f2bf((acc[i][jn][r] + bv) * sc);
        }
      }
    }
  }
}

// sigma: LDS K-row rho holds global key sigma(rho) so the S^T C-layout fragment
// coincides in-lane with the PV B-operand fragment (no cross-lane routing).
// rho = [nt2 nt1 nt0 | g1 g0 | r1 r0] -> sigma = [nt2 nt1 | g1 g0 | nt0 | r1 r0]
__device__ __forceinline__ int sigma_row(int rho) {
  return ((rho >> 5) << 5) | (((rho >> 2) & 3) << 3) | (((rho >> 4) & 1) << 2) | (rho & 3);
}

// stage one 128-key K tile (rows sigma-permuted) + V^T tile into LDS
__device__ __forceinline__ void stage_kv512(const short* __restrict__ Kt,
                                            const short* __restrict__ Vtt,
                                            short* ksb, short* vsb, int tid) {
#pragma unroll
  for (int t = 0; t < 2; t++) {
    int p = tid + t * 512;
    int krow = p >> 3, kchk = (p & 7) ^ (krow & 7);
    gl_lds16(Kt + (size_t)sigma_row(krow) * 64 + kchk * 8, ksb + p * 8);
    int dv = p >> 4, vchk = (p & 15) ^ (dv & 15);
    gl_lds16(Vtt + (size_t)dv * 2048 + vchk * 8, vsb + p * 8);
  }
}

// ---------- flash attention (S^T form, split-slice 512-thread blocks, sigma-K) ----------
// Block (bh, pr): 8 waves; wave w owns slice w of tile qhi=15-pr (mt0) and of
// tile qlo=pr (mt1), sharing one double-buffered KV stream of (16-pr) tiles.
// K rows sigma-permuted in LDS => P fragments for PV are in-lane (no shuffles).
__global__ __launch_bounds__(512, 2) void k_attn(const short* __restrict__ Q,
                                                 const short* __restrict__ K,
                                                 const short* __restrict__ Vt,
                                                 short* __restrict__ O) {
  __shared__ short Ks[2][128 * 64];  // 2x16 KB [key_lds][d], 8-chunk XOR swizzle
  __shared__ short Vs[2][64 * 128];  // 2x16 KB [d][key], 16-chunk XOR swizzle
  const int tid = threadIdx.x;       // 0..511
  const int lane = tid & 63;
  const int w = tid >> 6;            // 0..7 : 16-query slice index within each tile
  const int quad = lane >> 4, cq = lane & 15;
  const int bh = blockIdx.y;
  const int bb = bh >> 4, h = bh & 15;
  const size_t base = (size_t)bh * (2048 * 64);
  const int pr = blockIdx.x;         // 0..7
  const int qhi = 15 - pr, qlo = pr;
  const int jmax = qhi;
  const int qloc = w * 16 + cq;      // within-tile query row (same for both slices)

  // Q B-frags straight from global (16B/lane): mt0 -> tile qhi, mt1 -> tile qlo
  bf16x8 qf[2][2];
#pragma unroll
  for (int mt = 0; mt < 2; mt++) {
    const int qt = mt ? qlo : qhi;
#pragma unroll
    for (int kd = 0; kd < 2; kd++)
      qf[mt][kd] = *(const bf16x8*)(Q + base +
          (size_t)(qt * 128 + w * 16 + cq) * 64 + (kd * 4 + quad) * 8);
  }

  stage_kv512(K + base, Vt + base, Ks[0], Vs[0], tid);

  f32x4 o[2][4] = {};
  float m_run[2] = {-1e30f, -1e30f};
  float l_run[2] = {0.f, 0.f};

  for (int j = 0; j <= jmax; j++) {
    const int cur = j & 1;
    __syncthreads();  // buf[cur] staged; buf[cur^1] fully consumed
    if (j < jmax)
      stage_kv512(K + base + (size_t)(j + 1) * 128 * 64, Vt + base + (j + 1) * 128,
                  Ks[cur ^ 1], Vs[cur ^ 1], tid);
    const short* ks = Ks[cur];
    const short* vs = Vs[cur];
    const bool act1 = (j <= qlo);  // block-uniform

    // S^T[key][q] : 128 keys x 16 queries per active slice (K-frags shared)
    // s[mt][nt][r] at quad g corresponds to ACTUAL key 32*(nt>>1)+8g+4*(nt&1)+r
    f32x4 s[2][8] = {};
    if (act1) {
#pragma unroll
      for (int kd = 0; kd < 2; kd++)
#pragma unroll
        for (int nt = 0; nt < 8; nt++) {
          int krow = nt * 16 + cq;
          bf16x8 kf = *(const bf16x8*)(ks + krow * 64 + ((kd * 4 + quad) ^ (krow & 7)) * 8);
          s[0][nt] = __builtin_amdgcn_mfma_f32_16x16x32_bf16(kf, qf[0][kd], s[0][nt], 0, 0, 0);
          s[1][nt] = __builtin_amdgcn_mfma_f32_16x16x32_bf16(kf, qf[1][kd], s[1][nt], 0, 0, 0);
        }
    } else {
#pragma unroll
      for (int kd = 0; kd < 2; kd++)
#pragma unroll
        for (int nt = 0; nt < 8; nt++) {
          int krow = nt * 16 + cq;
          bf16x8 kf = *(const bf16x8*)(ks + krow * 64 + ((kd * 4 + quad) ^ (krow & 7)) * 8);
          s[0][nt] = __builtin_amdgcn_mfma_f32_16x16x32_bf16(kf, qf[0][kd], s[0][nt], 0, 0, 0);
        }
    }

    bf16x8 pf[2][4];
    const int nmt = act1 ? 2 : 1;
#pragma unroll
    for (int mt = 0; mt < 2; mt++) {
      if (mt >= nmt) break;  // block-uniform
      const bool diag = (j == (mt ? qlo : qhi));
      float mx = -1e30f;
      if (diag) {
#pragma unroll
        for (int nt = 0; nt < 8; nt++)
#pragma unroll
          for (int r = 0; r < 4; r++) {
            // actual key index under sigma
            int key = (nt >> 1) * 32 + (nt & 1) * 4 + r;  // + quad*8 at runtime
            float v = (key + quad * 8 > qloc) ? -1e30f : s[mt][nt][r];
            s[mt][nt][r] = v;
            mx = fmaxf(mx, v);
          }
      } else {
#pragma unroll
        for (int nt = 0; nt < 8; nt++)
#pragma unroll
          for (int r = 0; r < 4; r++) mx = fmaxf(mx, s[mt][nt][r]);
      }
      mx = fmaxf(mx, __shfl_xor(mx, 16));
      mx = fmaxf(mx, __shfl_xor(mx, 32));
      const float mn = fmaxf(m_run[mt], mx);
      const float alpha = fexp2(m_run[mt] - mn);
      m_run[mt] = mn;
      float lt = 0.f;
#pragma unroll
      for (int nt = 0; nt < 8; nt++)
#pragma unroll
        for (int r = 0; r < 4; r++) {
          float p = fexp2(s[mt][nt][r] - mn);
          s[mt][nt][r] = p;
          lt += p;
        }
      l_run[mt] = l_run[mt] * alpha + lt;
#pragma unroll
      for (int dn = 0; dn < 4; dn++) o[mt][dn] *= alpha;
      // P -> PV B-frag: IN-LANE pack (sigma makes layouts coincide)
#pragma unroll
      for (int kt = 0; kt < 4; kt++) {
        i32x4 ow;
        ow[0] = pk2bf(s[mt][2 * kt][0], s[mt][2 * kt][1]);
        ow[1] = pk2bf(s[mt][2 * kt][2], s[mt][2 * kt][3]);
        ow[2] = pk2bf(s[mt][2 * kt + 1][0], s[mt][2 * kt + 1][1]);
        ow[3] = pk2bf(s[mt][2 * kt + 1][2], s[mt][2 * kt + 1][3]);
        pf[mt][kt] = __builtin_bit_cast(bf16x8, ow);
      }
    }

    // O^T += Vt * P  (V-frags shared across active slices; V unpermuted)
    if (act1) {
#pragma unroll
      for (int kt = 0; kt < 4; kt++)
#pragma unroll
        for (int dn = 0; dn < 4; dn++) {
          int drow = dn * 16 + cq;
          bf16x8 vtf = *(const bf16x8*)(vs + drow * 128 + ((kt * 4 + quad) ^ (drow & 15)) * 8);
          o[0][dn] = __builtin_amdgcn_mfma_f32_16x16x32_bf16(vtf, pf[0][kt], o[0][dn], 0, 0, 0);
          o[1][dn] = __builtin_amdgcn_mfma_f32_16x16x32_bf16(vtf, pf[1][kt], o[1][dn], 0, 0, 0);
        }
    } else {
#pragma unroll
      for (int kt = 0; kt < 4; kt++)
#pragma unroll
        for (int dn = 0; dn < 4; dn++) {
          int drow = dn * 16 + cq;
          bf16x8 vtf = *(const bf16x8*)(vs + drow * 128 + ((kt * 4 + quad) ^ (drow & 15)) * 8);
          o[0][dn] = __builtin_amdgcn_mfma_f32_16x16x32_bf16(vtf, pf[0][kt], o[0][dn], 0, 0, 0);
        }
    }
  }

  // epilogue: reduce l across quads, normalize, pack 4 consecutive d -> 8B store
#pragma unroll
  for (int mt = 0; mt < 2; mt++) {
    const int qt = mt ? qlo : qhi;
    float lf = l_run[mt];
    lf += __shfl_xor(lf, 16);
    lf += __shfl_xor(lf, 32);
    const float inv = 1.f / lf;
    const size_t rb = ((size_t)(bb * 2048 + qt * 128 + w * 16 + cq)) * 1024 + h * 64;
#pragma unroll
    for (int dn = 0; dn < 4; dn++) {
      int d0 = pk2bf(o[mt][dn][0] * inv, o[mt][dn][1] * inv);
      int d1 = pk2bf(o[mt][dn][2] * inv, o[mt][dn][3] * inv);
      *(int2*)(O + rb + dn * 16 + quad * 4) = make_int2(d0, d1);
    }
  }
}

// ---------- out GEMM (BK=32): out[8192,1024] = AO @ WoutT^T + b (fp32 out) ----------
__global__ __launch_bounds__(256) void k_out_gemm(const short* __restrict__ A,
                                                  const short* __restrict__ B,
                                                  const float* __restrict__ bias,
                                                  float* __restrict__ out) {
  __shared__ short As[128 * 32];
  __shared__ short Bs[128 * 32];
  const int tid = threadIdx.x;
  const int lane = tid & 63;
  const int w = tid >> 6;
  const int g = lane >> 4, c = lane & 15;
  const int m0 = blockIdx.y * 128, n0 = blockIdx.x * 128;
  const int wm = (w >> 1) * 64, wn = (w & 1) * 64;
  f32x4 acc[4][4] = {};
  const int p0 = tid, p1 = tid + 256;
  const int rowA0 = p0 >> 2, logA0 = (p0 & 3) ^ ((p0 >> 3) & 3);
  const int rowA1 = p1 >> 2, logA1 = (p1 & 3) ^ ((p1 >> 3) & 3);
  const short* a0 = A + (size_t)(m0 + rowA0) * 1024 + logA0 * 8;
  const short* a1 = A + (size_t)(m0 + rowA1) * 1024 + logA1 * 8;
  const short* b0 = B + (size_t)(n0 + rowA0) * 1024 + logA0 * 8;
  const short* b1 = B + (size_t)(n0 + rowA1) * 1024 + logA1 * 8;
  short* lA0 = As + p0 * 8; short* lA1 = As + p1 * 8;
  short* lB0 = Bs + p0 * 8; short* lB1 = Bs + p1 * 8;

  for (int k0 = 0; k0 < 1024; k0 += 32) {
    gl_lds16(a0 + k0, lA0);
    gl_lds16(a1 + k0, lA1);
    gl_lds16(b0 + k0, lB0);
    gl_lds16(b1 + k0, lB1);
    __syncthreads();
    bf16x8 af[4], bfr[4];
#pragma unroll
    for (int t = 0; t < 4; t++) {
      int ra = wm + t * 16 + c;
      af[t] = *(const bf16x8*)(As + ra * 32 + (g ^ ((ra >> 1) & 3)) * 8);
      int rb = wn + t * 16 + c;
      bfr[t] = *(const bf16x8*)(Bs + rb * 32 + (g ^ ((rb >> 1) & 3)) * 8);
    }
#pragma unroll
    for (int i = 0; i < 4; i++)
#pragma unroll
      for (int jn = 0; jn < 4; jn++)
        acc[i][jn] = __builtin_amdgcn_mfma_f32_16x16x32_bf16(af[i], bfr[jn], acc[i][jn], 0, 0, 0);
    __syncthreads();
  }
#pragma unroll
  for (int jn = 0; jn < 4; jn++) {
    const int col = n0 + wn + jn * 16 + c;
    const float bv = bias[col];
#pragma unroll
    for (int i = 0; i < 4; i++) {
#pragma unroll
      for (int r = 0; r < 4; r++) {
        const int row = m0 + wm + i * 16 + g * 4 + r;
        out[(size_t)row * 1024 + col] = acc[i][jn][r] + bv;
      }
    }
  }
}

// ---------- launch ----------
extern "C" void kernel_launch(void* const* d_in, const int* in_sizes, int n_in,
                              void* d_out, int out_size, void* d_ws, size_t ws_size,
                              hipStream_t stream) {
  const float* x     = (const float*)d_in[0];
  const float* w_in  = (const float*)d_in[1];
  const float* b_in  = (const float*)d_in[2];
  const float* w_out = (const float*)d_in[3];
  const float* b_out = (const float*)d_in[4];
  float* out = (float*)d_out;
  char* ws = (char*)d_ws;
  short* x_bf   = (short*)(ws);                      // 16 MB  [8192,1024] bf16
  short* w_inT  = (short*)(ws + (16ull << 20));      //  6 MB  [3072,1024] bf16
  short* w_outT = (short*)(ws + (22ull << 20));      //  2 MB  [1024,1024] bf16
  short* qb     = (short*)(ws + (24ull << 20));      // 16 MB  [B,H,L,64]  bf16 (pre-scaled)
  short* kb     = (short*)(ws + (40ull << 20));      // 16 MB  [B,H,L,64]  bf16
  short* vtb    = (short*)(ws + (56ull << 20));      // 16 MB  [B,H,64,L]  bf16
  short* ao     = (short*)(ws + (72ull << 20));      // 16 MB  [B,L,H*64]  bf16

  k_convert_x<<<dim3(4096), dim3(256), 0, stream>>>(x, x_bf);
  k_transpose_cvt<<<dim3(96, 32), dim3(32, 8), 0, stream>>>(w_in, w_inT, 1024, 3072);
  k_transpose_cvt<<<dim3(32, 32), dim3(32, 8), 0, stream>>>(w_out, w_outT, 1024, 1024);
  k_qkv_gemm<<<dim3(24, 64), dim3(256), 0, stream>>>(x_bf, w_inT, b_in, qb, kb, vtb);
  k_attn<<<dim3(8, 64), dim3(512), 0, stream>>>(qb, kb, vtb, ao);
  k_out_gemm<<<dim3(8, 64), dim3(256), 0, stream>>>(ao, w_outT, b_out, out);
}